// Round 25
// baseline (286.347 us; speedup 1.0000x reference)
//
#include <hip/hip_runtime.h>

// MetaLayer: edge MLP + mean-aggregate + node MLP. fp32 in/out, int32 idx.
// cnt placement ledger (R21-R24): separate cnt stream costs 30-44us in ANY
// home (contends with edge's pattern-rate-saturated atomic/gather streams).
// R25: ELIMINATE the separate stream - degree accumulated as column 64 of
// the aggregation rows themselves (aggb widened to 72 bf16/row; one extra
// pk-atomic(+1.0) per edge from mrow==0 lanes, same L2 lines as the edge's
// feature atomics). bf16 integer-exact to 256 >> max degree (~60). 3 launches.

typedef __attribute__((ext_vector_type(8))) short bf16x8;   // MFMA A/B frag
typedef __attribute__((ext_vector_type(4))) float f4;       // MFMA C/D frag
typedef __attribute__((ext_vector_type(8))) unsigned short us8;

constexpr int NN  = 50000;
constexpr int NE  = 800000;
constexpr int FN  = 64;
constexpr int FE  = 64;
constexpr int HID = 128;
constexpr int K1  = 2 * FN + FE; // 192
constexpr int K2  = FN + FE;     // 128
constexpr int AGS = 72;          // aggb row stride (bf16): 64 feat + cnt + pad
constexpr int GRID_E    = 2500;  // edge blocks
constexpr int TPB_TILES = 5;     // tiles per block; 2500*5*64 = NE
// fused prep ranges
constexpr int ZAGG_TOT = NN * AGS / 8; // 450000: zero aggb, us8 stores
constexpr int PACK_TOT = 7168;         // weight pack items
constexpr int XCVT_TOT = NN * FN / 8;  // 400000: x->bf16
constexpr int PREP_TOT = ZAGG_TOT + PACK_TOT + XCVT_TOT;

__device__ __forceinline__ float b2f(unsigned short u) {
  union { unsigned int i; float f; } v; v.i = ((unsigned int)u) << 16; return v.f;
}
__device__ __forceinline__ unsigned short f2b(float f) {
  union { float f; unsigned int i; } v; v.f = f;
  unsigned int r = v.i + 0x7FFFu + ((v.i >> 16) & 1u);
  return (unsigned short)(r >> 16);
}
// 16 fp32 (4 f4 regs) -> 16 bf16 LDS
__device__ __forceinline__ void st16(const f4* r, unsigned short* dst) {
  us8 o0, o1;
#pragma unroll
  for (int j = 0; j < 4; j++) {
    o0[j] = f2b(r[0][j]); o0[4 + j] = f2b(r[1][j]);
    o1[j] = f2b(r[2][j]); o1[4 + j] = f2b(r[3][j]);
  }
  *(us8*)dst = o0; *(us8*)(dst + 8) = o1;
}
__device__ __forceinline__ void ld16(const float* p, f4* r) {
  const f4* pp = (const f4*)p;
  r[0] = pp[0]; r[1] = pp[1]; r[2] = pp[2]; r[3] = pp[3];
}
__device__ __forceinline__ f4 MF(bf16x8 a, bf16x8 b, f4 c) {
  return __builtin_amdgcn_mfma_f32_16x16x32_bf16(a, b, c, 0, 0, 0);
}
__device__ __forceinline__ void pk_atomic_add_bf16(unsigned short* addr, unsigned int data) {
  asm volatile("global_atomic_pk_add_bf16 %0, %1, off" :: "v"(addr), "v"(data) : "memory");
}

// fused prep: [zero aggb(+cnt col) | pack weights | x->bf16]
__global__ void prep_kernel(const float* __restrict__ We1, const float* __restrict__ We2,
                            const float* __restrict__ Wn1, const float* __restrict__ Wn2,
                            const float* __restrict__ x,
                            unsigned short* __restrict__ P, unsigned short* __restrict__ xb,
                            unsigned short* __restrict__ aggb) {
  int idx = blockIdx.x * 256 + threadIdx.x;
  if (idx < ZAGG_TOT) {
    *(us8*)(aggb + (size_t)idx * 8) = (us8)0;
  } else if (idx < ZAGG_TOT + PACK_TOT) {
    int w = idx - ZAGG_TOT;
    const float* W; unsigned short* Pd; int N;
    if (w < 3072)      { W = We1; Pd = P; N = HID; }
    else if (w < 4096) { W = We2; Pd = P + 24576; N = FE;  w -= 3072; }
    else if (w < 6144) { W = Wn1; Pd = P + 32768; N = HID; w -= 4096; }
    else               { W = Wn2; Pd = P + 49152; N = FN;  w -= 6144; }
    const int l  = w & 63;
    const int nt = (w >> 6) % (N >> 4);
    const int s  = w / ((N >> 4) << 6);
    const int col = nt * 16 + (l & 15);
    const int k0  = s * 32 + (l >> 4) * 8;
    us8 o;
#pragma unroll
    for (int j = 0; j < 8; j++) o[j] = f2b(W[(size_t)(k0 + j) * N + col]);
    *(us8*)(Pd + (size_t)w * 8) = o;
  } else if (idx < PREP_TOT) {
    const int i = idx - ZAGG_TOT - PACK_TOT;
    const f4* p = (const f4*)(x + (size_t)i * 8);
    f4 a = p[0], b = p[1];
    us8 o;
#pragma unroll
    for (int j = 0; j < 4; j++) { o[j] = f2b(a[j]); o[4 + j] = f2b(b[j]); }
    *(us8*)(xb + (size_t)i * 8) = o;
  }
}

// ---- edge MLP (MFMA): 5-tile pipeline, double-buffered sA, separate sH,
// 2 barriers/tile, bf16 x-gathers; degree fused into aggb col 64.
__global__ __launch_bounds__(256) void edge_mlp(
    const unsigned short* __restrict__ xb, const int* __restrict__ ei,
    const float* __restrict__ ea,
    const unsigned short* __restrict__ P1, const float* __restrict__ be1,
    const unsigned short* __restrict__ P2, const float* __restrict__ be2,
    float* __restrict__ eout, unsigned short* __restrict__ aggb) {
  __shared__ unsigned short sA[2][64][200]; // 51.2KB; 400B stride
  __shared__ unsigned short sH[64][136];    // 17.4KB (separate)
  __shared__ int sC[2][64];
  const int tid  = threadIdx.x;
  const int wave = tid >> 6, lane = tid & 63;
  const int mrow = lane & 15, kq = lane >> 4;
  const int el = tid >> 2, q = tid & 3;  // staging role: 4 threads/edge

  us8 rx0[2], rx1[2];         // in-flight bf16 x-gathers (16 bf16 each)
  f4  rea[4];                 // in-flight fp32 ea quarter
  int rN, cN;                 // in-flight indices (one tile further)
  int cStage;                 // dst id matching current data regs

  { // prologue: tile0 gather -> regs -> sA[0]; tile1 indices
    const int ge = blockIdx.x * 64 + el;
    const int r = ei[ge], c = ei[NE + ge];
    cStage = c;
    const us8* pr = (const us8*)(xb + (size_t)r * FN + q * 16);
    rx0[0] = pr[0]; rx0[1] = pr[1];
    const us8* pc = (const us8*)(xb + (size_t)c * FN + q * 16);
    rx1[0] = pc[0]; rx1[1] = pc[1];
    ld16(ea + (size_t)ge * FE + q * 16, rea);
    const int ge1 = (blockIdx.x + GRID_E) * 64 + el;
    rN = ei[ge1];
    cN = ei[NE + ge1];
    sC[0][el] = cStage;
    *(us8*)&sA[0][el][q * 16]          = rx0[0];
    *(us8*)&sA[0][el][q * 16 + 8]      = rx0[1];
    *(us8*)&sA[0][el][64 + q * 16]     = rx1[0];
    *(us8*)&sA[0][el][64 + q * 16 + 8] = rx1[1];
    st16(rea, &sA[0][el][128 + q * 16]);
  }

  for (int j = 0; j < TPB_TILES; j++) {
    const int cur = j & 1, nxt = cur ^ 1;
    const int e0 = (blockIdx.x + j * GRID_E) * 64;
    __syncthreads(); // sA[cur] writes visible; prev GEMM2 sH reads complete

    if (j + 1 < TPB_TILES) { // prefetch tile j+1 (indices already arrived)
      const int rr = rN, cc = cN;
      cStage = cc;
      const int geN = e0 + GRID_E * 64 + el;
      const us8* pr = (const us8*)(xb + (size_t)rr * FN + q * 16);
      rx0[0] = pr[0]; rx0[1] = pr[1];
      const us8* pc = (const us8*)(xb + (size_t)cc * FN + q * 16);
      rx1[0] = pc[0]; rx1[1] = pc[1];
      ld16(ea + (size_t)geN * FE + q * 16, rea);
      if (j + 2 < TPB_TILES) {
        const int ge2 = e0 + 2 * GRID_E * 64 + el;
        rN = ei[ge2];
        cN = ei[NE + ge2];
      }
    }
    __builtin_amdgcn_sched_barrier(0); // pin prefetch issue before GEMM1

    // GEMM1: [64x192]@[192x128], wave -> ntiles {2w,2w+1}
    f4 acc[4][2];
#pragma unroll
    for (int m = 0; m < 4; m++) { acc[m][0] = (f4)0.f; acc[m][1] = (f4)0.f; }
    const int nt0 = wave * 2;
#pragma unroll
    for (int s = 0; s < 6; s++) {
      bf16x8 b0 = *(const bf16x8*)(P1 + (((size_t)s * 8 + nt0)     * 64 + lane) * 8);
      bf16x8 b1 = *(const bf16x8*)(P1 + (((size_t)s * 8 + nt0 + 1) * 64 + lane) * 8);
#pragma unroll
      for (int m = 0; m < 4; m++) {
        bf16x8 a = *(const bf16x8*)&sA[cur][m * 16 + mrow][s * 32 + kq * 8];
        acc[m][0] = MF(a, b0, acc[m][0]);
        acc[m][1] = MF(a, b1, acc[m][1]);
      }
    }

    { // bias + relu -> sH. D: row=(lane>>4)*4+i, col=lane&15
      const int c0 = nt0 * 16 + mrow, c1 = c0 + 16;
      const float bb0 = be1[c0], bb1 = be1[c1];
      const int rb = kq * 4;
#pragma unroll
      for (int m = 0; m < 4; m++)
#pragma unroll
        for (int i = 0; i < 4; i++) {
          sH[m * 16 + rb + i][c0] = f2b(fmaxf(acc[m][0][i] + bb0, 0.f));
          sH[m * 16 + rb + i][c1] = f2b(fmaxf(acc[m][1][i] + bb1, 0.f));
        }
    }
    __syncthreads(); // sH ready (sA[cur] reads also complete)

    // GEMM2: [64x128]@[128x64], wave -> ntile w
    f4 a2[4];
#pragma unroll
    for (int m = 0; m < 4; m++) a2[m] = (f4)0.f;
#pragma unroll
    for (int s = 0; s < 4; s++) {
      bf16x8 b = *(const bf16x8*)(P2 + (((size_t)s * 4 + wave) * 64 + lane) * 8);
#pragma unroll
      for (int m = 0; m < 4; m++) {
        bf16x8 a = *(const bf16x8*)&sH[m * 16 + mrow][s * 32 + kq * 8];
        a2[m] = MF(a, b, a2[m]);
      }
    }

    { // epilogue: bias -> eout fp32; pk-bf16 atomics (even lanes, col pairs);
      // degree +1.0 into col 64 (mrow==0 lanes, same rows as feature atomics)
      const int col = wave * 16 + mrow;
      const float bb = be2[col];
      const int rb = kq * 4;
      const bool even = ((lane & 1) == 0);
#pragma unroll
      for (int m = 0; m < 4; m++)
#pragma unroll
        for (int i = 0; i < 4; i++) {
          const int er = m * 16 + rb + i;
          const float v = a2[m][i] + bb;
          eout[(size_t)(e0 + er) * FE + col] = v;
          const float vp = __shfl_xor(v, 1); // partner col^1 value
          if (even) {
            const unsigned int pk =
                (unsigned int)f2b(v) | ((unsigned int)f2b(vp) << 16);
            pk_atomic_add_bf16(aggb + ((size_t)sC[cur][er] * AGS + col), pk);
          }
        }
      if (wave == 0 && mrow == 0) { // one count atomic per edge (lanes 0/16/32/48)
        const unsigned int one = (unsigned int)f2b(1.0f); // lo=+1.0, hi=+0.0
#pragma unroll
        for (int m = 0; m < 4; m++)
#pragma unroll
          for (int i = 0; i < 4; i++) {
            const int er = m * 16 + rb + i;
            pk_atomic_add_bf16(aggb + ((size_t)sC[cur][er] * AGS + 64), one);
          }
      }
    }

    if (j + 1 < TPB_TILES) { // stage tile j+1 into sA[nxt] (overlaps epilogue)
      sC[nxt][el] = cStage;
      *(us8*)&sA[nxt][el][q * 16]          = rx0[0];
      *(us8*)&sA[nxt][el][q * 16 + 8]      = rx0[1];
      *(us8*)&sA[nxt][el][64 + q * 16]     = rx1[0];
      *(us8*)&sA[nxt][el][64 + q * 16 + 8] = rx1[1];
      st16(rea, &sA[nxt][el][128 + q * 16]);
    }
  }
}

// ---- node MLP (MFMA): 32 nodes/block, 4 waves, 1563 blocks. bf16 inputs;
// degree read from aggb col 64.
__global__ __launch_bounds__(256) void node_mlp(
    const unsigned short* __restrict__ xb, const unsigned short* __restrict__ aggb,
    const unsigned short* __restrict__ P1, const float* __restrict__ bn1,
    const unsigned short* __restrict__ P2, const float* __restrict__ bn2,
    float* __restrict__ xout) {
  __shared__ unsigned short sA[32][136]; // 8.7KB; 272B stride
  unsigned short (*sH)[136] = (unsigned short(*)[136])&sA[0][0]; // alias
  const int tid = threadIdx.x;
  const int n0  = blockIdx.x * 32;

  { // stage: 8 threads/node; q<4: x 16-col quarters (bf16); q>=4: agg mean
    const int nl = tid >> 3, q = tid & 7;
    const int gn = n0 + nl;
    if (gn < NN) {
      if (q < 4) {
        const us8* p = (const us8*)(xb + (size_t)gn * FN + q * 16);
        *(us8*)&sA[nl][q * 16]     = p[0];
        *(us8*)&sA[nl][q * 16 + 8] = p[1];
      } else {
        const float deg = b2f(aggb[(size_t)gn * AGS + 64]);
        const float inv = 1.0f / fmaxf(deg, 1.0f);
        const int q4 = q - 4;
        const us8* pa = (const us8*)(aggb + (size_t)gn * AGS + q4 * 16);
#pragma unroll
        for (int seg = 0; seg < 2; seg++) {
          us8 a = pa[seg];
          us8 o;
#pragma unroll
          for (int jj = 0; jj < 8; jj++) o[jj] = f2b(b2f(a[jj]) * inv);
          *(us8*)&sA[nl][64 + q4 * 16 + seg * 8] = o;
        }
      }
    } else {
      us8 z = (us8)0;
      *(us8*)&sA[nl][(q & 3) * 16]     = z;
      *(us8*)&sA[nl][(q & 3) * 16 + 8] = z;
      *(us8*)&sA[nl][64 + (q & 3) * 16]     = z;
      *(us8*)&sA[nl][64 + (q & 3) * 16 + 8] = z;
    }
  }
  __syncthreads();

  const int wave = tid >> 6, lane = tid & 63;
  const int mrow = lane & 15, kq = lane >> 4;

  // GEMM1: [32x128]@[128x128]
  f4 acc[2][2];
#pragma unroll
  for (int m = 0; m < 2; m++) { acc[m][0] = (f4)0.f; acc[m][1] = (f4)0.f; }
  const int nt0 = wave * 2;
#pragma unroll
  for (int s = 0; s < 4; s++) {
    bf16x8 b0 = *(const bf16x8*)(P1 + (((size_t)s * 8 + nt0)     * 64 + lane) * 8);
    bf16x8 b1 = *(const bf16x8*)(P1 + (((size_t)s * 8 + nt0 + 1) * 64 + lane) * 8);
#pragma unroll
    for (int m = 0; m < 2; m++) {
      bf16x8 a = *(const bf16x8*)&sA[m * 16 + mrow][s * 32 + kq * 8];
      acc[m][0] = MF(a, b0, acc[m][0]);
      acc[m][1] = MF(a, b1, acc[m][1]);
    }
  }
  __syncthreads();

  {
    const int c0 = nt0 * 16 + mrow, c1 = c0 + 16;
    const float bb0 = bn1[c0], bb1 = bn1[c1];
    const int rb = kq * 4;
#pragma unroll
    for (int m = 0; m < 2; m++)
#pragma unroll
      for (int i = 0; i < 4; i++) {
        sH[m * 16 + rb + i][c0] = f2b(fmaxf(acc[m][0][i] + bb0, 0.f));
        sH[m * 16 + rb + i][c1] = f2b(fmaxf(acc[m][1][i] + bb1, 0.f));
      }
  }
  __syncthreads();

  // GEMM2: [32x128]@[128x64]
  f4 a2[2];
  a2[0] = (f4)0.f; a2[1] = (f4)0.f;
#pragma unroll
  for (int s = 0; s < 4; s++) {
    bf16x8 b = *(const bf16x8*)(P2 + (((size_t)s * 4 + wave) * 64 + lane) * 8);
#pragma unroll
    for (int m = 0; m < 2; m++) {
      bf16x8 a = *(const bf16x8*)&sH[m * 16 + mrow][s * 32 + kq * 8];
      a2[m] = MF(a, b, a2[m]);
    }
  }
  {
    const int col = wave * 16 + mrow;
    const float bb = bn2[col];
    const int rb = kq * 4;
#pragma unroll
    for (int m = 0; m < 2; m++)
#pragma unroll
      for (int i = 0; i < 4; i++) {
        const int gn = n0 + m * 16 + rb + i;
        if (gn < NN) xout[(size_t)gn * FN + col] = a2[m][i] + bb;
      }
  }
}

extern "C" void kernel_launch(void* const* d_in, const int* in_sizes, int n_in,
                              void* d_out, int out_size, void* d_ws, size_t ws_size,
                              hipStream_t stream) {
  if (n_in != 11) return;
  if (in_sizes[0] != NN * FN) return;
  if (in_sizes[1] != 2 * NE) return;
  if (in_sizes[2] != NE * FE) return;
  if (out_size != NN * FN + NE * FE) return;
  // ws: aggb 7.2MB + P 114KB + xb 6.4MB
  if (ws_size < (size_t)NN * AGS * 2 + 114688 + (size_t)NN * FN * 2) return;

  const float* x   = (const float*)d_in[0];
  const int*   ei  = (const int*)d_in[1];
  const float* ea  = (const float*)d_in[2];
  const float* We1 = (const float*)d_in[3];
  const float* be1 = (const float*)d_in[4];
  const float* We2 = (const float*)d_in[5];
  const float* be2 = (const float*)d_in[6];
  const float* Wn1 = (const float*)d_in[7];
  const float* bn1 = (const float*)d_in[8];
  const float* Wn2 = (const float*)d_in[9];
  const float* bn2 = (const float*)d_in[10];

  float* xout = (float*)d_out;
  float* eout = xout + (size_t)NN * FN;

  unsigned short* aggb = (unsigned short*)d_ws;          // [NN*AGS] bf16
  unsigned short* P  = aggb + (size_t)NN * AGS;          // packed weights
  unsigned short* Pe1 = P;              // 6*8*64*8  = 24576 shorts
  unsigned short* Pe2 = P + 24576;      // 4*4*64*8  =  8192
  unsigned short* Pn1 = P + 32768;      // 4*8*64*8  = 16384
  unsigned short* Pn2 = P + 49152;      //             8192
  unsigned short* xb  = P + 57344;      // [NN*FN] bf16 x

  prep_kernel<<<(PREP_TOT + 255) / 256, 256, 0, stream>>>(
      We1, We2, Wn1, Wn2, x, P, xb, aggb);
  edge_mlp<<<GRID_E, 256, 0, stream>>>(xb, ei, ea, Pe1, be1, Pe2, be2, eout, aggb);
  node_mlp<<<(NN + 31) / 32, 256, 0, stream>>>(xb, aggb, Pn1, bn1, Pn2, bn2, xout);
}

// Round 26
// 244.338 us; speedup vs baseline: 1.1719x; 1.1719x over previous
//
#include <hip/hip_runtime.h>

// MetaLayer: edge MLP + mean-aggregate + node MLP. fp32 in/out, int32 idx.
// R25 failure root-caused via WRITE_SIZE: AGS=72 -> 144B rows, half start
// mid-sector -> feature atomics span 5 sectors (+50MB write-through). R26:
// AGS=80 (160B rows = 32B-multiple): feature span stays 4-sector aligned,
// degree column 64 lands in the row's 5th sector (same L2 line, no separate
// stream). Otherwise identical to R25. 3 launches.

typedef __attribute__((ext_vector_type(8))) short bf16x8;   // MFMA A/B frag
typedef __attribute__((ext_vector_type(4))) float f4;       // MFMA C/D frag
typedef __attribute__((ext_vector_type(8))) unsigned short us8;

constexpr int NN  = 50000;
constexpr int NE  = 800000;
constexpr int FN  = 64;
constexpr int FE  = 64;
constexpr int HID = 128;
constexpr int K1  = 2 * FN + FE; // 192
constexpr int K2  = FN + FE;     // 128
constexpr int AGS = 80;          // aggb row stride (bf16): 160B = 5 sectors
constexpr int GRID_E    = 2500;  // edge blocks
constexpr int TPB_TILES = 5;     // tiles per block; 2500*5*64 = NE
// fused prep ranges
constexpr int ZAGG_TOT = NN * AGS / 8; // 500000: zero aggb, us8 stores
constexpr int PACK_TOT = 7168;         // weight pack items
constexpr int XCVT_TOT = NN * FN / 8;  // 400000: x->bf16
constexpr int PREP_TOT = ZAGG_TOT + PACK_TOT + XCVT_TOT;

__device__ __forceinline__ float b2f(unsigned short u) {
  union { unsigned int i; float f; } v; v.i = ((unsigned int)u) << 16; return v.f;
}
__device__ __forceinline__ unsigned short f2b(float f) {
  union { float f; unsigned int i; } v; v.f = f;
  unsigned int r = v.i + 0x7FFFu + ((v.i >> 16) & 1u);
  return (unsigned short)(r >> 16);
}
// 16 fp32 (4 f4 regs) -> 16 bf16 LDS
__device__ __forceinline__ void st16(const f4* r, unsigned short* dst) {
  us8 o0, o1;
#pragma unroll
  for (int j = 0; j < 4; j++) {
    o0[j] = f2b(r[0][j]); o0[4 + j] = f2b(r[1][j]);
    o1[j] = f2b(r[2][j]); o1[4 + j] = f2b(r[3][j]);
  }
  *(us8*)dst = o0; *(us8*)(dst + 8) = o1;
}
__device__ __forceinline__ void ld16(const float* p, f4* r) {
  const f4* pp = (const f4*)p;
  r[0] = pp[0]; r[1] = pp[1]; r[2] = pp[2]; r[3] = pp[3];
}
__device__ __forceinline__ f4 MF(bf16x8 a, bf16x8 b, f4 c) {
  return __builtin_amdgcn_mfma_f32_16x16x32_bf16(a, b, c, 0, 0, 0);
}
__device__ __forceinline__ void pk_atomic_add_bf16(unsigned short* addr, unsigned int data) {
  asm volatile("global_atomic_pk_add_bf16 %0, %1, off" :: "v"(addr), "v"(data) : "memory");
}

// fused prep: [zero aggb(+cnt col) | pack weights | x->bf16]
__global__ void prep_kernel(const float* __restrict__ We1, const float* __restrict__ We2,
                            const float* __restrict__ Wn1, const float* __restrict__ Wn2,
                            const float* __restrict__ x,
                            unsigned short* __restrict__ P, unsigned short* __restrict__ xb,
                            unsigned short* __restrict__ aggb) {
  int idx = blockIdx.x * 256 + threadIdx.x;
  if (idx < ZAGG_TOT) {
    *(us8*)(aggb + (size_t)idx * 8) = (us8)0;
  } else if (idx < ZAGG_TOT + PACK_TOT) {
    int w = idx - ZAGG_TOT;
    const float* W; unsigned short* Pd; int N;
    if (w < 3072)      { W = We1; Pd = P; N = HID; }
    else if (w < 4096) { W = We2; Pd = P + 24576; N = FE;  w -= 3072; }
    else if (w < 6144) { W = Wn1; Pd = P + 32768; N = HID; w -= 4096; }
    else               { W = Wn2; Pd = P + 49152; N = FN;  w -= 6144; }
    const int l  = w & 63;
    const int nt = (w >> 6) % (N >> 4);
    const int s  = w / ((N >> 4) << 6);
    const int col = nt * 16 + (l & 15);
    const int k0  = s * 32 + (l >> 4) * 8;
    us8 o;
#pragma unroll
    for (int j = 0; j < 8; j++) o[j] = f2b(W[(size_t)(k0 + j) * N + col]);
    *(us8*)(Pd + (size_t)w * 8) = o;
  } else if (idx < PREP_TOT) {
    const int i = idx - ZAGG_TOT - PACK_TOT;
    const f4* p = (const f4*)(x + (size_t)i * 8);
    f4 a = p[0], b = p[1];
    us8 o;
#pragma unroll
    for (int j = 0; j < 4; j++) { o[j] = f2b(a[j]); o[4 + j] = f2b(b[j]); }
    *(us8*)(xb + (size_t)i * 8) = o;
  }
}

// ---- edge MLP (MFMA): 5-tile pipeline, double-buffered sA, separate sH,
// 2 barriers/tile, bf16 x-gathers; degree fused into aggb col 64.
__global__ __launch_bounds__(256) void edge_mlp(
    const unsigned short* __restrict__ xb, const int* __restrict__ ei,
    const float* __restrict__ ea,
    const unsigned short* __restrict__ P1, const float* __restrict__ be1,
    const unsigned short* __restrict__ P2, const float* __restrict__ be2,
    float* __restrict__ eout, unsigned short* __restrict__ aggb) {
  __shared__ unsigned short sA[2][64][200]; // 51.2KB; 400B stride
  __shared__ unsigned short sH[64][136];    // 17.4KB (separate)
  __shared__ int sC[2][64];
  const int tid  = threadIdx.x;
  const int wave = tid >> 6, lane = tid & 63;
  const int mrow = lane & 15, kq = lane >> 4;
  const int el = tid >> 2, q = tid & 3;  // staging role: 4 threads/edge

  us8 rx0[2], rx1[2];         // in-flight bf16 x-gathers (16 bf16 each)
  f4  rea[4];                 // in-flight fp32 ea quarter
  int rN, cN;                 // in-flight indices (one tile further)
  int cStage;                 // dst id matching current data regs

  { // prologue: tile0 gather -> regs -> sA[0]; tile1 indices
    const int ge = blockIdx.x * 64 + el;
    const int r = ei[ge], c = ei[NE + ge];
    cStage = c;
    const us8* pr = (const us8*)(xb + (size_t)r * FN + q * 16);
    rx0[0] = pr[0]; rx0[1] = pr[1];
    const us8* pc = (const us8*)(xb + (size_t)c * FN + q * 16);
    rx1[0] = pc[0]; rx1[1] = pc[1];
    ld16(ea + (size_t)ge * FE + q * 16, rea);
    const int ge1 = (blockIdx.x + GRID_E) * 64 + el;
    rN = ei[ge1];
    cN = ei[NE + ge1];
    sC[0][el] = cStage;
    *(us8*)&sA[0][el][q * 16]          = rx0[0];
    *(us8*)&sA[0][el][q * 16 + 8]      = rx0[1];
    *(us8*)&sA[0][el][64 + q * 16]     = rx1[0];
    *(us8*)&sA[0][el][64 + q * 16 + 8] = rx1[1];
    st16(rea, &sA[0][el][128 + q * 16]);
  }

  for (int j = 0; j < TPB_TILES; j++) {
    const int cur = j & 1, nxt = cur ^ 1;
    const int e0 = (blockIdx.x + j * GRID_E) * 64;
    __syncthreads(); // sA[cur] writes visible; prev GEMM2 sH reads complete

    if (j + 1 < TPB_TILES) { // prefetch tile j+1 (indices already arrived)
      const int rr = rN, cc = cN;
      cStage = cc;
      const int geN = e0 + GRID_E * 64 + el;
      const us8* pr = (const us8*)(xb + (size_t)rr * FN + q * 16);
      rx0[0] = pr[0]; rx0[1] = pr[1];
      const us8* pc = (const us8*)(xb + (size_t)cc * FN + q * 16);
      rx1[0] = pc[0]; rx1[1] = pc[1];
      ld16(ea + (size_t)geN * FE + q * 16, rea);
      if (j + 2 < TPB_TILES) {
        const int ge2 = e0 + 2 * GRID_E * 64 + el;
        rN = ei[ge2];
        cN = ei[NE + ge2];
      }
    }
    __builtin_amdgcn_sched_barrier(0); // pin prefetch issue before GEMM1

    // GEMM1: [64x192]@[192x128], wave -> ntiles {2w,2w+1}
    f4 acc[4][2];
#pragma unroll
    for (int m = 0; m < 4; m++) { acc[m][0] = (f4)0.f; acc[m][1] = (f4)0.f; }
    const int nt0 = wave * 2;
#pragma unroll
    for (int s = 0; s < 6; s++) {
      bf16x8 b0 = *(const bf16x8*)(P1 + (((size_t)s * 8 + nt0)     * 64 + lane) * 8);
      bf16x8 b1 = *(const bf16x8*)(P1 + (((size_t)s * 8 + nt0 + 1) * 64 + lane) * 8);
#pragma unroll
      for (int m = 0; m < 4; m++) {
        bf16x8 a = *(const bf16x8*)&sA[cur][m * 16 + mrow][s * 32 + kq * 8];
        acc[m][0] = MF(a, b0, acc[m][0]);
        acc[m][1] = MF(a, b1, acc[m][1]);
      }
    }

    { // bias + relu -> sH. D: row=(lane>>4)*4+i, col=lane&15
      const int c0 = nt0 * 16 + mrow, c1 = c0 + 16;
      const float bb0 = be1[c0], bb1 = be1[c1];
      const int rb = kq * 4;
#pragma unroll
      for (int m = 0; m < 4; m++)
#pragma unroll
        for (int i = 0; i < 4; i++) {
          sH[m * 16 + rb + i][c0] = f2b(fmaxf(acc[m][0][i] + bb0, 0.f));
          sH[m * 16 + rb + i][c1] = f2b(fmaxf(acc[m][1][i] + bb1, 0.f));
        }
    }
    __syncthreads(); // sH ready (sA[cur] reads also complete)

    // GEMM2: [64x128]@[128x64], wave -> ntile w
    f4 a2[4];
#pragma unroll
    for (int m = 0; m < 4; m++) a2[m] = (f4)0.f;
#pragma unroll
    for (int s = 0; s < 4; s++) {
      bf16x8 b = *(const bf16x8*)(P2 + (((size_t)s * 4 + wave) * 64 + lane) * 8);
#pragma unroll
      for (int m = 0; m < 4; m++) {
        bf16x8 a = *(const bf16x8*)&sH[m * 16 + mrow][s * 32 + kq * 8];
        a2[m] = MF(a, b, a2[m]);
      }
    }

    { // epilogue: bias -> eout fp32; pk-bf16 atomics (even lanes, col pairs);
      // degree +1.0 into col 64 (wave 0, mrow==0 lanes; same rows/L2 lines)
      const int col = wave * 16 + mrow;
      const float bb = be2[col];
      const int rb = kq * 4;
      const bool even = ((lane & 1) == 0);
#pragma unroll
      for (int m = 0; m < 4; m++)
#pragma unroll
        for (int i = 0; i < 4; i++) {
          const int er = m * 16 + rb + i;
          const float v = a2[m][i] + bb;
          eout[(size_t)(e0 + er) * FE + col] = v;
          const float vp = __shfl_xor(v, 1); // partner col^1 value
          if (even) {
            const unsigned int pk =
                (unsigned int)f2b(v) | ((unsigned int)f2b(vp) << 16);
            pk_atomic_add_bf16(aggb + ((size_t)sC[cur][er] * AGS + col), pk);
          }
        }
      if (wave == 0 && mrow == 0) { // one count atomic per edge (lanes 0/16/32/48)
        const unsigned int one = (unsigned int)f2b(1.0f); // lo=+1.0, hi=+0.0
#pragma unroll
        for (int m = 0; m < 4; m++)
#pragma unroll
          for (int i = 0; i < 4; i++) {
            const int er = m * 16 + rb + i;
            pk_atomic_add_bf16(aggb + ((size_t)sC[cur][er] * AGS + 64), one);
          }
      }
    }

    if (j + 1 < TPB_TILES) { // stage tile j+1 into sA[nxt] (overlaps epilogue)
      sC[nxt][el] = cStage;
      *(us8*)&sA[nxt][el][q * 16]          = rx0[0];
      *(us8*)&sA[nxt][el][q * 16 + 8]      = rx0[1];
      *(us8*)&sA[nxt][el][64 + q * 16]     = rx1[0];
      *(us8*)&sA[nxt][el][64 + q * 16 + 8] = rx1[1];
      st16(rea, &sA[nxt][el][128 + q * 16]);
    }
  }
}

// ---- node MLP (MFMA): 32 nodes/block, 4 waves, 1563 blocks. bf16 inputs;
// degree read from aggb col 64.
__global__ __launch_bounds__(256) void node_mlp(
    const unsigned short* __restrict__ xb, const unsigned short* __restrict__ aggb,
    const unsigned short* __restrict__ P1, const float* __restrict__ bn1,
    const unsigned short* __restrict__ P2, const float* __restrict__ bn2,
    float* __restrict__ xout) {
  __shared__ unsigned short sA[32][136]; // 8.7KB; 272B stride
  unsigned short (*sH)[136] = (unsigned short(*)[136])&sA[0][0]; // alias
  const int tid = threadIdx.x;
  const int n0  = blockIdx.x * 32;

  { // stage: 8 threads/node; q<4: x 16-col quarters (bf16); q>=4: agg mean
    const int nl = tid >> 3, q = tid & 7;
    const int gn = n0 + nl;
    if (gn < NN) {
      if (q < 4) {
        const us8* p = (const us8*)(xb + (size_t)gn * FN + q * 16);
        *(us8*)&sA[nl][q * 16]     = p[0];
        *(us8*)&sA[nl][q * 16 + 8] = p[1];
      } else {
        const float deg = b2f(aggb[(size_t)gn * AGS + 64]);
        const float inv = 1.0f / fmaxf(deg, 1.0f);
        const int q4 = q - 4;
        const us8* pa = (const us8*)(aggb + (size_t)gn * AGS + q4 * 16);
#pragma unroll
        for (int seg = 0; seg < 2; seg++) {
          us8 a = pa[seg];
          us8 o;
#pragma unroll
          for (int jj = 0; jj < 8; jj++) o[jj] = f2b(b2f(a[jj]) * inv);
          *(us8*)&sA[nl][64 + q4 * 16 + seg * 8] = o;
        }
      }
    } else {
      us8 z = (us8)0;
      *(us8*)&sA[nl][(q & 3) * 16]     = z;
      *(us8*)&sA[nl][(q & 3) * 16 + 8] = z;
      *(us8*)&sA[nl][64 + (q & 3) * 16]     = z;
      *(us8*)&sA[nl][64 + (q & 3) * 16 + 8] = z;
    }
  }
  __syncthreads();

  const int wave = tid >> 6, lane = tid & 63;
  const int mrow = lane & 15, kq = lane >> 4;

  // GEMM1: [32x128]@[128x128]
  f4 acc[2][2];
#pragma unroll
  for (int m = 0; m < 2; m++) { acc[m][0] = (f4)0.f; acc[m][1] = (f4)0.f; }
  const int nt0 = wave * 2;
#pragma unroll
  for (int s = 0; s < 4; s++) {
    bf16x8 b0 = *(const bf16x8*)(P1 + (((size_t)s * 8 + nt0)     * 64 + lane) * 8);
    bf16x8 b1 = *(const bf16x8*)(P1 + (((size_t)s * 8 + nt0 + 1) * 64 + lane) * 8);
#pragma unroll
    for (int m = 0; m < 2; m++) {
      bf16x8 a = *(const bf16x8*)&sA[m * 16 + mrow][s * 32 + kq * 8];
      acc[m][0] = MF(a, b0, acc[m][0]);
      acc[m][1] = MF(a, b1, acc[m][1]);
    }
  }
  __syncthreads();

  {
    const int c0 = nt0 * 16 + mrow, c1 = c0 + 16;
    const float bb0 = bn1[c0], bb1 = bn1[c1];
    const int rb = kq * 4;
#pragma unroll
    for (int m = 0; m < 2; m++)
#pragma unroll
      for (int i = 0; i < 4; i++) {
        sH[m * 16 + rb + i][c0] = f2b(fmaxf(acc[m][0][i] + bb0, 0.f));
        sH[m * 16 + rb + i][c1] = f2b(fmaxf(acc[m][1][i] + bb1, 0.f));
      }
  }
  __syncthreads();

  // GEMM2: [32x128]@[128x64]
  f4 a2[2];
  a2[0] = (f4)0.f; a2[1] = (f4)0.f;
#pragma unroll
  for (int s = 0; s < 4; s++) {
    bf16x8 b = *(const bf16x8*)(P2 + (((size_t)s * 4 + wave) * 64 + lane) * 8);
#pragma unroll
    for (int m = 0; m < 2; m++) {
      bf16x8 a = *(const bf16x8*)&sH[m * 16 + mrow][s * 32 + kq * 8];
      a2[m] = MF(a, b, a2[m]);
    }
  }
  {
    const int col = wave * 16 + mrow;
    const float bb = bn2[col];
    const int rb = kq * 4;
#pragma unroll
    for (int m = 0; m < 2; m++)
#pragma unroll
      for (int i = 0; i < 4; i++) {
        const int gn = n0 + m * 16 + rb + i;
        if (gn < NN) xout[(size_t)gn * FN + col] = a2[m][i] + bb;
      }
  }
}

extern "C" void kernel_launch(void* const* d_in, const int* in_sizes, int n_in,
                              void* d_out, int out_size, void* d_ws, size_t ws_size,
                              hipStream_t stream) {
  if (n_in != 11) return;
  if (in_sizes[0] != NN * FN) return;
  if (in_sizes[1] != 2 * NE) return;
  if (in_sizes[2] != NE * FE) return;
  if (out_size != NN * FN + NE * FE) return;
  // ws: aggb 8MB + P 114KB + xb 6.4MB
  if (ws_size < (size_t)NN * AGS * 2 + 114688 + (size_t)NN * FN * 2) return;

  const float* x   = (const float*)d_in[0];
  const int*   ei  = (const int*)d_in[1];
  const float* ea  = (const float*)d_in[2];
  const float* We1 = (const float*)d_in[3];
  const float* be1 = (const float*)d_in[4];
  const float* We2 = (const float*)d_in[5];
  const float* be2 = (const float*)d_in[6];
  const float* Wn1 = (const float*)d_in[7];
  const float* bn1 = (const float*)d_in[8];
  const float* Wn2 = (const float*)d_in[9];
  const float* bn2 = (const float*)d_in[10];

  float* xout = (float*)d_out;
  float* eout = xout + (size_t)NN * FN;

  unsigned short* aggb = (unsigned short*)d_ws;          // [NN*AGS] bf16
  unsigned short* P  = aggb + (size_t)NN * AGS;          // packed weights
  unsigned short* Pe1 = P;              // 6*8*64*8  = 24576 shorts
  unsigned short* Pe2 = P + 24576;      // 4*4*64*8  =  8192
  unsigned short* Pn1 = P + 32768;      // 4*8*64*8  = 16384
  unsigned short* Pn2 = P + 49152;      //             8192
  unsigned short* xb  = P + 57344;      // [NN*FN] bf16 x

  prep_kernel<<<(PREP_TOT + 255) / 256, 256, 0, stream>>>(
      We1, We2, Wn1, Wn2, x, P, xb, aggb);
  edge_mlp<<<GRID_E, 256, 0, stream>>>(xb, ei, ea, Pe1, be1, Pe2, be2, eout, aggb);
  node_mlp<<<(NN + 31) / 32, 256, 0, stream>>>(xb, aggb, Pn1, bn1, Pn2, bn2, xout);
}